// Round 1
// baseline (1395.487 us; speedup 1.0000x reference)
//
#include <hip/hip_runtime.h>
#include <hip/hip_bf16.h>
#include <math.h>

#define HH  256      // d_model
#define NHD 32       // state halves
#define LL  8192     // sequence length
#define BB  16       // batch
#define HN  (HH*NHD) // 8192
#define BH  (BB*HH)  // 4096

// ---------------------------------------------------------------------------
// Param precompute (double precision, tiny): w = exp(dtA), c = 2*C*expm1(dtA)/A
// Layout P[k*HN + h*NHD + n], k: 0=wr 1=wi 2=c0r 3=c0i 4=c1r 5=c1i
// ---------------------------------------------------------------------------
__global__ void precomp_kernel(const float* __restrict__ log_dt,
                               const float* __restrict__ A_real,
                               const float* __restrict__ A_imag,
                               const float* __restrict__ C_real,
                               const float* __restrict__ C_imag,
                               float* __restrict__ P) {
  int i = blockIdx.x * blockDim.x + threadIdx.x;
  if (i >= HN) return;
  int h = i >> 5;
  double dt  = exp((double)log_dt[h]);
  double Are = -exp((double)A_real[i]);
  double Aim = (double)A_imag[i];
  double ar = Are * dt, ai = Aim * dt;
  double ea = exp(ar);
  double wr = ea * cos(ai), wi = ea * sin(ai);
  double em_r = wr - 1.0, em_i = wi;                 // expm1(dtA)
  double den = Are * Are + Aim * Aim;
  double rr = (em_r * Are + em_i * Aim) / den;       // expm1(dtA)/A
  double ri = (em_i * Are - em_r * Aim) / den;
  P[0*HN + i] = (float)wr;
  P[1*HN + i] = (float)wi;
  {
    double cr = (double)C_real[i], ci = (double)C_imag[i];
    P[2*HN + i] = (float)(2.0 * (cr * rr - ci * ri));
    P[3*HN + i] = (float)(2.0 * (cr * ri + ci * rr));
  }
  {
    double cr = (double)C_real[HN + i], ci = (double)C_imag[HN + i];
    P[4*HN + i] = (float)(2.0 * (cr * rr - ci * ri));
    P[5*HN + i] = (float)(2.0 * (cr * ri + ci * rr));
  }
}

// ---------------------------------------------------------------------------
// W_out (512,256) -> WT (256,512) so GEMM loads coalesce over o
// ---------------------------------------------------------------------------
__global__ void wt_kernel(const float* __restrict__ W, float* __restrict__ WT) {
  int idx = blockIdx.x * blockDim.x + threadIdx.x;   // idx = h*512 + o
  if (idx >= 512 * HH) return;
  int o = idx & 511, h = idx >> 9;
  WT[idx] = W[o * HH + h];
}

// ---------------------------------------------------------------------------
// x (L, B*H) -> U (B*H, L)  tiled transpose
// ---------------------------------------------------------------------------
__global__ void transpose_kernel(const float* __restrict__ x, float* __restrict__ U) {
  __shared__ float tile[32][33];
  int gx = blockIdx.x * 32;   // p = b*H + h
  int gy = blockIdx.y * 32;   // t
  int tx = threadIdx.x, ty = threadIdx.y;
  #pragma unroll
  for (int k2 = 0; k2 < 4; ++k2)
    tile[ty + 8*k2][tx] = x[(size_t)(gy + ty + 8*k2) * BH + gx + tx];
  __syncthreads();
  #pragma unroll
  for (int k2 = 0; k2 < 4; ++k2)
    U[(size_t)(gx + ty + 8*k2) * LL + gy + tx] = tile[tx][ty + 8*k2];
}

// ---------------------------------------------------------------------------
// 16-lane row reduction via DPP row_ror adds (pure VALU, no LDS pipe)
// ---------------------------------------------------------------------------
template<int CTRL>
__device__ __forceinline__ float dpp_add(float v) {
  int t = __builtin_amdgcn_update_dpp(0, __float_as_int(v), CTRL, 0xF, 0xF, true);
  return v + __int_as_float(t);
}
__device__ __forceinline__ float row16_sum(float v) {
  v = dpp_add<0x121>(v);  // row_ror:1
  v = dpp_add<0x122>(v);  // row_ror:2
  v = dpp_add<0x124>(v);  // row_ror:4
  v = dpp_add<0x128>(v);  // row_ror:8
  return v;
}

// ---------------------------------------------------------------------------
// Backward (anti-causal) scan: sB[t] = u[t] + w*sB[t+1];
// partial y_b[t] = sum_n Re(c1_n * sB[t+1])  (factor 2 folded into c)
// 16-lane groups, 2 complex states per lane (n = gl and gl+16).
// ---------------------------------------------------------------------------
__global__ __launch_bounds__(256) void bwd_kernel(const float* __restrict__ U,
                                                  const float* __restrict__ P,
                                                  float* __restrict__ YB) {
  int tid = threadIdx.x;
  int gl  = tid & 15;
  int p   = blockIdx.x * 16 + (tid >> 4);
  int h   = p & (HH - 1);
  int i0  = h * NHD + gl, i1 = i0 + 16;
  float wr0 = P[i0],        wi0 = P[HN + i0];
  float wr1 = P[i1],        wi1 = P[HN + i1];
  float cr0 = P[4*HN + i0], ci0 = P[5*HN + i0];
  float cr1 = P[4*HN + i1], ci1 = P[5*HN + i1];
  const float* up = U  + (size_t)p * LL;
  float*       yp = YB + (size_t)p * LL;
  float s0r = 0.f, s0i = 0.f, s1r = 0.f, s1i = 0.f;
  int srcbase = tid & 48;
  for (int chunk = LL - 16; chunk >= 0; chunk -= 16) {
    float uv = up[chunk + gl];
    float cb[16];
    #pragma unroll
    for (int k = 15; k >= 0; --k) {
      // contribution for t = chunk+k uses sB[t+1] (current state)
      float c = cr0 * s0r;
      c = fmaf(-ci0, s0i, c);
      c = fmaf( cr1, s1r, c);
      c = fmaf(-ci1, s1i, c);
      cb[k] = c;
      float ub = __shfl(uv, srcbase | k, 64);
      // s = u[t] + w*s
      float t0  = fmaf(wr0, s0r, ub);
      float ni0 = fmaf(wi0, s0r, wr0 * s0i);
      s0r = fmaf(-wi0, s0i, t0);
      s0i = ni0;
      float t1  = fmaf(wr1, s1r, ub);
      float ni1 = fmaf(wi1, s1r, wr1 * s1i);
      s1r = fmaf(-wi1, s1i, t1);
      s1i = ni1;
    }
    #pragma unroll
    for (int k = 0; k < 16; ++k) cb[k] = row16_sum(cb[k]);
    float myv = 0.f;
    #pragma unroll
    for (int k = 0; k < 16; ++k) myv = (gl == k) ? cb[k] : myv;
    yp[chunk + gl] = myv;
  }
}

// ---------------------------------------------------------------------------
// Forward scan + combine: s[t] = w*s[t-1] + u[t]; y_f = sum Re(c0*s[t]);
// y = y_f + y_b + D*u; gelu(tanh approx); write over U in place.
// ---------------------------------------------------------------------------
__global__ __launch_bounds__(256) void fwd_kernel(float* __restrict__ U,
                                                  const float* __restrict__ P,
                                                  const float* __restrict__ YB,
                                                  const float* __restrict__ Dv) {
  int tid = threadIdx.x;
  int gl  = tid & 15;
  int p   = blockIdx.x * 16 + (tid >> 4);
  int h   = p & (HH - 1);
  int i0  = h * NHD + gl, i1 = i0 + 16;
  float wr0 = P[i0],        wi0 = P[HN + i0];
  float wr1 = P[i1],        wi1 = P[HN + i1];
  float cr0 = P[2*HN + i0], ci0 = P[3*HN + i0];
  float cr1 = P[2*HN + i1], ci1 = P[3*HN + i1];
  float dh  = Dv[h];
  float*       up  = U  + (size_t)p * LL;
  const float* ybp = YB + (size_t)p * LL;
  float s0r = 0.f, s0i = 0.f, s1r = 0.f, s1i = 0.f;
  int srcbase = tid & 48;
  for (int chunk = 0; chunk < LL; chunk += 16) {
    float uv  = up[chunk + gl];
    float ybv = ybp[chunk + gl];
    float cb[16];
    #pragma unroll
    for (int k = 0; k < 16; ++k) {
      float ub = __shfl(uv, srcbase | k, 64);
      // s = w*s + u[t]
      float t0  = fmaf(wr0, s0r, ub);
      float ni0 = fmaf(wi0, s0r, wr0 * s0i);
      s0r = fmaf(-wi0, s0i, t0);
      s0i = ni0;
      float t1  = fmaf(wr1, s1r, ub);
      float ni1 = fmaf(wi1, s1r, wr1 * s1i);
      s1r = fmaf(-wi1, s1i, t1);
      s1i = ni1;
      float c = cr0 * s0r;
      c = fmaf(-ci0, s0i, c);
      c = fmaf( cr1, s1r, c);
      c = fmaf(-ci1, s1i, c);
      cb[k] = c;
    }
    #pragma unroll
    for (int k = 0; k < 16; ++k) cb[k] = row16_sum(cb[k]);
    float myv = 0.f;
    #pragma unroll
    for (int k = 0; k < 16; ++k) myv = (gl == k) ? cb[k] : myv;
    float yv = myv + ybv + dh * uv;
    float inner = 0.7978845608028654f * (yv + 0.044715f * yv * yv * yv);
    float g = 0.5f * yv * (1.0f + tanhf(inner));
    up[chunk + gl] = g;
  }
}

// ---------------------------------------------------------------------------
// z = W_out @ y + b; out = z[:256] * sigmoid(z[256:])
// Block: 256 threads, 32 l-columns; thread o computes rows o and o+256.
// ---------------------------------------------------------------------------
__global__ __launch_bounds__(256, 4) void gemm_kernel(const float* __restrict__ Y,
                                                      const float* __restrict__ WT,
                                                      const float* __restrict__ bvec,
                                                      float* __restrict__ out) {
  __shared__ float ytile[HH][36];
  int tid = threadIdx.x;
  int b   = blockIdx.x >> 8;
  int l0  = (blockIdx.x & 255) << 5;
  const float* yrow = Y + ((size_t)b * HH + tid) * LL + l0;
  float4* drow = (float4*)&ytile[tid][0];
  #pragma unroll
  for (int jj = 0; jj < 8; ++jj)
    drow[jj] = ((const float4*)yrow)[jj];
  __syncthreads();
  float acc0[32], acc1[32];
  #pragma unroll
  for (int j = 0; j < 32; ++j) { acc0[j] = 0.f; acc1[j] = 0.f; }
  #pragma unroll 2
  for (int h = 0; h < HH; ++h) {
    float w0 = WT[h * 512 + tid];
    float w1 = WT[h * 512 + 256 + tid];
    const float4* r = (const float4*)&ytile[h][0];
    #pragma unroll
    for (int jj = 0; jj < 8; ++jj) {
      float4 y4 = r[jj];
      acc0[4*jj+0] = fmaf(w0, y4.x, acc0[4*jj+0]);
      acc0[4*jj+1] = fmaf(w0, y4.y, acc0[4*jj+1]);
      acc0[4*jj+2] = fmaf(w0, y4.z, acc0[4*jj+2]);
      acc0[4*jj+3] = fmaf(w0, y4.w, acc0[4*jj+3]);
      acc1[4*jj+0] = fmaf(w1, y4.x, acc1[4*jj+0]);
      acc1[4*jj+1] = fmaf(w1, y4.y, acc1[4*jj+1]);
      acc1[4*jj+2] = fmaf(w1, y4.z, acc1[4*jj+2]);
      acc1[4*jj+3] = fmaf(w1, y4.w, acc1[4*jj+3]);
    }
  }
  float b0 = bvec[tid], b1 = bvec[HH + tid];
  float* orow = out + ((size_t)b * HH + tid) * LL + l0;
  #pragma unroll
  for (int j = 0; j < 32; ++j) {
    float z1 = acc0[j] + b0;
    float z2 = acc1[j] + b1;
    orow[j] = z1 * (1.0f / (1.0f + expf(-z2)));
  }
}

// ---------------------------------------------------------------------------
extern "C" void kernel_launch(void* const* d_in, const int* in_sizes, int n_in,
                              void* d_out, int out_size, void* d_ws, size_t ws_size,
                              hipStream_t stream) {
  const float* x      = (const float*)d_in[0];
  const float* log_dt = (const float*)d_in[1];
  const float* A_real = (const float*)d_in[2];
  const float* A_imag = (const float*)d_in[3];
  const float* C_real = (const float*)d_in[4];
  const float* C_imag = (const float*)d_in[5];
  const float* Dv     = (const float*)d_in[6];
  const float* W      = (const float*)d_in[7];
  const float* bvec   = (const float*)d_in[8];
  float* out = (float*)d_out;

  char* ws = (char*)d_ws;
  float* P  = (float*)ws;                    // 6*HN floats  = 192 KB
  float* WT = (float*)(ws + 262144);         // 512*256 floats = 512 KB
  float* U  = (float*)(ws + (1 << 20));      // BH*LL floats = 128 MB

  precomp_kernel<<<HN / 256, 256, 0, stream>>>(log_dt, A_real, A_imag, C_real, C_imag, P);
  wt_kernel<<<512, 256, 0, stream>>>(W, WT);
  transpose_kernel<<<dim3(BH / 32, LL / 32), dim3(32, 8), 0, stream>>>(x, U);
  bwd_kernel<<<BH / 16, 256, 0, stream>>>(U, P, (float*)d_out);
  fwd_kernel<<<BH / 16, 256, 0, stream>>>(U, P, (const float*)d_out, Dv);
  gemm_kernel<<<BB * (LL / 32), 256, 0, stream>>>(U, WT, bvec, out);
}

// Round 2
// 1075.920 us; speedup vs baseline: 1.2970x; 1.2970x over previous
//
#include <hip/hip_runtime.h>
#include <hip/hip_bf16.h>
#include <math.h>

#define HH  256      // d_model
#define NHD 32       // state halves
#define LL  8192     // sequence length
#define BB  16       // batch
#define HN  (HH*NHD) // 8192
#define BH  (BB*HH)  // 4096
#define LC  512      // chunk length
#define NG  (LL/LC)  // 16 chunks per row
#define NIT (LC/16)  // 32 sub-iters per chunk

// ---------------------------------------------------------------------------
// Param precompute (double precision, tiny): w = exp(dtA), c = 2*C*expm1(dtA)/A
// Layout P[k*HN + h*NHD + n], k: 0=wr 1=wi 2=c0r 3=c0i 4=c1r 5=c1i 6=wLr 7=wLi
// where wL = w^LC (chunk decay), computed in double.
// ---------------------------------------------------------------------------
__global__ void precomp_kernel(const float* __restrict__ log_dt,
                               const float* __restrict__ A_real,
                               const float* __restrict__ A_imag,
                               const float* __restrict__ C_real,
                               const float* __restrict__ C_imag,
                               float* __restrict__ P) {
  int i = blockIdx.x * blockDim.x + threadIdx.x;
  if (i >= HN) return;
  int h = i >> 5;
  double dt  = exp((double)log_dt[h]);
  double Are = -exp((double)A_real[i]);
  double Aim = (double)A_imag[i];
  double ar = Are * dt, ai = Aim * dt;
  double ea = exp(ar);
  double wr = ea * cos(ai), wi = ea * sin(ai);
  double em_r = wr - 1.0, em_i = wi;                 // expm1(dtA)
  double den = Are * Are + Aim * Aim;
  double rr = (em_r * Are + em_i * Aim) / den;       // expm1(dtA)/A
  double ri = (em_i * Are - em_r * Aim) / den;
  P[0*HN + i] = (float)wr;
  P[1*HN + i] = (float)wi;
  {
    double cr = (double)C_real[i], ci = (double)C_imag[i];
    P[2*HN + i] = (float)(2.0 * (cr * rr - ci * ri));
    P[3*HN + i] = (float)(2.0 * (cr * ri + ci * rr));
  }
  {
    double cr = (double)C_real[HN + i], ci = (double)C_imag[HN + i];
    P[4*HN + i] = (float)(2.0 * (cr * rr - ci * ri));
    P[5*HN + i] = (float)(2.0 * (cr * ri + ci * rr));
  }
  {
    double arL = ar * (double)LC, aiL = ai * (double)LC;
    double eaL = exp(arL);
    P[6*HN + i] = (float)(eaL * cos(aiL));
    P[7*HN + i] = (float)(eaL * sin(aiL));
  }
}

// ---------------------------------------------------------------------------
// W_out (512,256) -> WT (256,512)
// ---------------------------------------------------------------------------
__global__ void wt_kernel(const float* __restrict__ W, float* __restrict__ WT) {
  int idx = blockIdx.x * blockDim.x + threadIdx.x;   // idx = h*512 + o
  if (idx >= 512 * HH) return;
  int o = idx & 511, h = idx >> 9;
  WT[idx] = W[o * HH + h];
}

// ---------------------------------------------------------------------------
// x (L, B*H) -> U (B*H, L)  tiled transpose
// ---------------------------------------------------------------------------
__global__ void transpose_kernel(const float* __restrict__ x, float* __restrict__ U) {
  __shared__ float tile[32][33];
  int gx = blockIdx.x * 32;   // p = b*H + h
  int gy = blockIdx.y * 32;   // t
  int tx = threadIdx.x, ty = threadIdx.y;
  #pragma unroll
  for (int k2 = 0; k2 < 4; ++k2)
    tile[ty + 8*k2][tx] = x[(size_t)(gy + ty + 8*k2) * BH + gx + tx];
  __syncthreads();
  #pragma unroll
  for (int k2 = 0; k2 < 4; ++k2)
    U[(size_t)(gx + ty + 8*k2) * LL + gy + tx] = tile[tx][ty + 8*k2];
}

// ---------------------------------------------------------------------------
// quad (4-lane) DPP helpers
// ---------------------------------------------------------------------------
template<int CTRL>
__device__ __forceinline__ float qbcast(float v) {
  int t = __builtin_amdgcn_update_dpp(0, __float_as_int(v), CTRL, 0xF, 0xF, true);
  return __int_as_float(t);
}
template<int CTRL>
__device__ __forceinline__ float qadd(float v) {
  int t = __builtin_amdgcn_update_dpp(0, __float_as_int(v), CTRL, 0xF, 0xF, true);
  return v + __int_as_float(t);
}
// 4-lane butterfly sum: qadd<0xB1> (swap 0<->1,2<->3) then qadd<0x4E> (swap pairs)

// ---------------------------------------------------------------------------
// step primitives: 8 complex states per lane
// ---------------------------------------------------------------------------
__device__ __forceinline__ void upd8(float ub, float (&sr)[8], float (&si)[8],
                                     const float (&wr)[8], const float (&wi)[8]) {
  #pragma unroll
  for (int q = 0; q < 8; ++q) {
    float t  = fmaf(wr[q], sr[q], ub);
    float ni = fmaf(wi[q], sr[q], wr[q] * si[q]);
    sr[q] = fmaf(-wi[q], si[q], t);
    si[q] = ni;
  }
}
__device__ __forceinline__ float fwd_step(float ub, float (&sr)[8], float (&si)[8],
    const float (&wr)[8], const float (&wi)[8],
    const float (&cr)[8], const float (&ci)[8]) {
  float c = 0.f;
  #pragma unroll
  for (int q = 0; q < 8; ++q) {
    float t  = fmaf(wr[q], sr[q], ub);
    float ni = fmaf(wi[q], sr[q], wr[q] * si[q]);
    sr[q] = fmaf(-wi[q], si[q], t);
    si[q] = ni;
    c = fmaf(cr[q], sr[q], c);
    c = fmaf(-ci[q], si[q], c);
  }
  return c;
}
__device__ __forceinline__ float bwd_step(float ub, float (&sr)[8], float (&si)[8],
    const float (&wr)[8], const float (&wi)[8],
    const float (&cr)[8], const float (&ci)[8]) {
  float c = 0.f;
  #pragma unroll
  for (int q = 0; q < 8; ++q) {
    c = fmaf(cr[q], sr[q], c);          // uses state BEFORE absorbing u[t]
    c = fmaf(-ci[q], si[q], c);
    float t  = fmaf(wr[q], sr[q], ub);
    float ni = fmaf(wi[q], sr[q], wr[q] * si[q]);
    sr[q] = fmaf(-wi[q], si[q], t);
    si[q] = ni;
  }
  return c;
}

// ---------------------------------------------------------------------------
// Pass A: per-(row,chunk) local final states, both directions, zero init.
// Group = 4 lanes; lane gl owns n = gl*8 .. gl*8+7. 64 groups/block.
// ---------------------------------------------------------------------------
__global__ __launch_bounds__(256) void scanA(const float* __restrict__ U,
                                             const float* __restrict__ P,
                                             float* __restrict__ SF,
                                             float* __restrict__ SB) {
  int tid = threadIdx.x;
  int gl  = tid & 3;
  int grp = (blockIdx.x << 6) | (tid >> 2);
  int p = grp >> 4, g = grp & (NG - 1), h = p & (HH - 1);
  const float* Pb = P + h * NHD + gl * 8;
  float wr[8], wi[8];
  #pragma unroll
  for (int q = 0; q < 8; ++q) { wr[q] = Pb[q]; wi[q] = Pb[HN + q]; }
  float fr[8], fi[8], br[8], bi[8];
  #pragma unroll
  for (int q = 0; q < 8; ++q) { fr[q] = 0.f; fi[q] = 0.f; br[q] = 0.f; bi[q] = 0.f; }
  size_t base = (size_t)p * LL + (size_t)g * LC;
  const float* up = U + base;

#define AF(J2, CMP) { float ubv = qbcast<(J2)*0x55>(uf.CMP); upd8(ubv, fr, fi, wr, wi); }
#define AB(J2, CMP) { float ubv = qbcast<(J2)*0x55>(ub4.CMP); upd8(ubv, br, bi, wr, wi); }
  for (int ii = 0; ii < NIT; ++ii) {
    float4 uf  = ((const float4*)(up + 16 * ii))[gl];
    float4 ub4 = ((const float4*)(up + (LC - 16) - 16 * ii))[gl];
    AF(0,x) AF(0,y) AF(0,z) AF(0,w)
    AF(1,x) AF(1,y) AF(1,z) AF(1,w)
    AF(2,x) AF(2,y) AF(2,z) AF(2,w)
    AF(3,x) AF(3,y) AF(3,z) AF(3,w)
    AB(3,w) AB(3,z) AB(3,y) AB(3,x)
    AB(2,w) AB(2,z) AB(2,y) AB(2,x)
    AB(1,w) AB(1,z) AB(1,y) AB(1,x)
    AB(0,w) AB(0,z) AB(0,y) AB(0,x)
  }
#undef AF
#undef AB
  float* of = SF + (size_t)grp * 64 + gl * 16;
  float* ob = SB + (size_t)grp * 64 + gl * 16;
  #pragma unroll
  for (int q = 0; q < 8; ++q) {
    of[2*q] = fr[q]; of[2*q+1] = fi[q];
    ob[2*q] = br[q]; ob[2*q+1] = bi[q];
  }
}

// ---------------------------------------------------------------------------
// Pass B: cross-chunk scan, in place: loc -> incoming state per chunk.
// One thread per (row p, state n). s_in[g] = loc[g-1] + wL * s_in[g-1].
// ---------------------------------------------------------------------------
__global__ __launch_bounds__(256) void scanB(const float* __restrict__ P,
                                             float* __restrict__ SF,
                                             float* __restrict__ SB) {
  int t = blockIdx.x * 256 + threadIdx.x;   // t = p*32 + n
  if (t >= BH * NHD) return;
  int p = t >> 5, n = t & 31, h = p & (HH - 1);
  float wlr = P[6*HN + h*NHD + n], wli = P[7*HN + h*NHD + n];
  {
    float* f = SF + (size_t)p * NG * 64 + 2 * n;
    float ar = 0.f, ai = 0.f;
    for (int g = 0; g < NG; ++g) {
      float lr = f[g*64], li = f[g*64+1];
      f[g*64] = ar; f[g*64+1] = ai;
      float nr = lr + wlr * ar - wli * ai;
      float ni = li + wlr * ai + wli * ar;
      ar = nr; ai = ni;
    }
  }
  {
    float* b = SB + (size_t)p * NG * 64 + 2 * n;
    float ar = 0.f, ai = 0.f;
    for (int g = NG - 1; g >= 0; --g) {
      float lr = b[g*64], li = b[g*64+1];
      b[g*64] = ar; b[g*64+1] = ai;
      float nr = lr + wlr * ar - wli * ai;
      float ni = li + wlr * ai + wli * ar;
      ar = nr; ai = ni;
    }
  }
}

// ---------------------------------------------------------------------------
// Pass C backward: y_b partials -> YB (d_out). Chunk right-to-left.
// ---------------------------------------------------------------------------
__global__ __launch_bounds__(256) void scanC_bwd(const float* __restrict__ U,
                                                 const float* __restrict__ P,
                                                 const float* __restrict__ Sin,
                                                 float* __restrict__ YB) {
  int tid = threadIdx.x;
  int gl  = tid & 3;
  int grp = (blockIdx.x << 6) | (tid >> 2);
  int p = grp >> 4, g = grp & (NG - 1), h = p & (HH - 1);
  const float* Pb = P + h * NHD + gl * 8;
  float wr[8], wi[8], cr[8], ci[8];
  #pragma unroll
  for (int q = 0; q < 8; ++q) {
    wr[q] = Pb[q];        wi[q] = Pb[HN + q];
    cr[q] = Pb[4*HN + q]; ci[q] = Pb[5*HN + q];
  }
  float sr[8], si[8];
  const float* sp = Sin + (size_t)grp * 64 + gl * 16;
  #pragma unroll
  for (int q = 0; q < 8; ++q) { sr[q] = sp[2*q]; si[q] = sp[2*q+1]; }
  size_t base = (size_t)p * LL + (size_t)g * LC;
  const float* up = U + base;
  float* yp = YB + base;

#define QB(J2, CMP, ACC) { \
    float ubv = qbcast<(J2)*0x55>(u4.CMP); \
    float c = bwd_step(ubv, sr, si, wr, wi, cr, ci); \
    c = qadd<0xB1>(c); c = qadd<0x4E>(c); \
    ACC = (gl == (J2)) ? c : ACC; }
  for (int ii = NIT - 1; ii >= 0; --ii) {
    float4 u4 = ((const float4*)(up + 16 * ii))[gl];
    float a0 = 0.f, a1 = 0.f, a2 = 0.f, a3 = 0.f;
    QB(3,w,a3) QB(3,z,a2) QB(3,y,a1) QB(3,x,a0)
    QB(2,w,a3) QB(2,z,a2) QB(2,y,a1) QB(2,x,a0)
    QB(1,w,a3) QB(1,z,a2) QB(1,y,a1) QB(1,x,a0)
    QB(0,w,a3) QB(0,z,a2) QB(0,y,a1) QB(0,x,a0)
    float4 o4; o4.x = a0; o4.y = a1; o4.z = a2; o4.w = a3;
    ((float4*)(yp + 16 * ii))[gl] = o4;
  }
#undef QB
}

// ---------------------------------------------------------------------------
// Pass C forward: combine y_f + y_b + D*u, gelu, write over U in place.
// ---------------------------------------------------------------------------
__device__ __forceinline__ float gelu_t(float y) {
  float y2 = y * y;
  float arg = 1.5957691216f * fmaf(0.044715f * y2, y, y);  // 2*0.79788456*(y+0.044715y^3)
  return y / (1.f + __expf(-arg));                          // y*sigmoid(2*inner)
}
__global__ __launch_bounds__(256) void scanC_fwd(float* __restrict__ U,
                                                 const float* __restrict__ P,
                                                 const float* __restrict__ Sin,
                                                 const float* __restrict__ YB,
                                                 const float* __restrict__ Dv) {
  int tid = threadIdx.x;
  int gl  = tid & 3;
  int grp = (blockIdx.x << 6) | (tid >> 2);
  int p = grp >> 4, g = grp & (NG - 1), h = p & (HH - 1);
  const float* Pb = P + h * NHD + gl * 8;
  float wr[8], wi[8], cr[8], ci[8];
  #pragma unroll
  for (int q = 0; q < 8; ++q) {
    wr[q] = Pb[q];        wi[q] = Pb[HN + q];
    cr[q] = Pb[2*HN + q]; ci[q] = Pb[3*HN + q];
  }
  float dh = Dv[h];
  float sr[8], si[8];
  const float* sp = Sin + (size_t)grp * 64 + gl * 16;
  #pragma unroll
  for (int q = 0; q < 8; ++q) { sr[q] = sp[2*q]; si[q] = sp[2*q+1]; }
  size_t base = (size_t)p * LL + (size_t)g * LC;
  float* up = U + base;
  const float* ybp = YB + base;

#define QF(J2, CMP, ACC) { \
    float ubv = qbcast<(J2)*0x55>(u4.CMP); \
    float c = fwd_step(ubv, sr, si, wr, wi, cr, ci); \
    c = qadd<0xB1>(c); c = qadd<0x4E>(c); \
    ACC = (gl == (J2)) ? c : ACC; }
  for (int ii = 0; ii < NIT; ++ii) {
    float4 u4  = ((const float4*)(up + 16 * ii))[gl];
    float4 yb4 = ((const float4*)(ybp + 16 * ii))[gl];
    float a0 = 0.f, a1 = 0.f, a2 = 0.f, a3 = 0.f;
    QF(0,x,a0) QF(0,y,a1) QF(0,z,a2) QF(0,w,a3)
    QF(1,x,a0) QF(1,y,a1) QF(1,z,a2) QF(1,w,a3)
    QF(2,x,a0) QF(2,y,a1) QF(2,z,a2) QF(2,w,a3)
    QF(3,x,a0) QF(3,y,a1) QF(3,z,a2) QF(3,w,a3)
    float4 o4;
    o4.x = gelu_t(a0 + yb4.x + dh * u4.x);
    o4.y = gelu_t(a1 + yb4.y + dh * u4.y);
    o4.z = gelu_t(a2 + yb4.z + dh * u4.z);
    o4.w = gelu_t(a3 + yb4.w + dh * u4.w);
    ((float4*)(up + 16 * ii))[gl] = o4;
  }
#undef QF
}

// ---------------------------------------------------------------------------
// z = W_out @ y + b; out = z[:256] * sigmoid(z[256:])
// ---------------------------------------------------------------------------
__global__ __launch_bounds__(256, 4) void gemm_kernel(const float* __restrict__ Y,
                                                      const float* __restrict__ WT,
                                                      const float* __restrict__ bvec,
                                                      float* __restrict__ out) {
  __shared__ float ytile[HH][36];
  int tid = threadIdx.x;
  int b   = blockIdx.x >> 8;
  int l0  = (blockIdx.x & 255) << 5;
  const float* yrow = Y + ((size_t)b * HH + tid) * LL + l0;
  float4* drow = (float4*)&ytile[tid][0];
  #pragma unroll
  for (int jj = 0; jj < 8; ++jj)
    drow[jj] = ((const float4*)yrow)[jj];
  __syncthreads();
  float acc0[32], acc1[32];
  #pragma unroll
  for (int j = 0; j < 32; ++j) { acc0[j] = 0.f; acc1[j] = 0.f; }
  #pragma unroll 2
  for (int h = 0; h < HH; ++h) {
    float w0 = WT[h * 512 + tid];
    float w1 = WT[h * 512 + 256 + tid];
    const float4* r = (const float4*)&ytile[h][0];
    #pragma unroll
    for (int jj = 0; jj < 8; ++jj) {
      float4 y4 = r[jj];
      acc0[4*jj+0] = fmaf(w0, y4.x, acc0[4*jj+0]);
      acc0[4*jj+1] = fmaf(w0, y4.y, acc0[4*jj+1]);
      acc0[4*jj+2] = fmaf(w0, y4.z, acc0[4*jj+2]);
      acc0[4*jj+3] = fmaf(w0, y4.w, acc0[4*jj+3]);
      acc1[4*jj+0] = fmaf(w1, y4.x, acc1[4*jj+0]);
      acc1[4*jj+1] = fmaf(w1, y4.y, acc1[4*jj+1]);
      acc1[4*jj+2] = fmaf(w1, y4.z, acc1[4*jj+2]);
      acc1[4*jj+3] = fmaf(w1, y4.w, acc1[4*jj+3]);
    }
  }
  float b0 = bvec[tid], b1 = bvec[HH + tid];
  float* orow = out + ((size_t)b * HH + tid) * LL + l0;
  #pragma unroll
  for (int j = 0; j < 32; ++j) {
    float z1 = acc0[j] + b0;
    float z2 = acc1[j] + b1;
    orow[j] = z1 * (1.0f / (1.0f + __expf(-z2)));
  }
}

// ---------------------------------------------------------------------------
extern "C" void kernel_launch(void* const* d_in, const int* in_sizes, int n_in,
                              void* d_out, int out_size, void* d_ws, size_t ws_size,
                              hipStream_t stream) {
  const float* x      = (const float*)d_in[0];
  const float* log_dt = (const float*)d_in[1];
  const float* A_real = (const float*)d_in[2];
  const float* A_imag = (const float*)d_in[3];
  const float* C_real = (const float*)d_in[4];
  const float* C_imag = (const float*)d_in[5];
  const float* Dv     = (const float*)d_in[6];
  const float* W      = (const float*)d_in[7];
  const float* bvec   = (const float*)d_in[8];
  float* out = (float*)d_out;

  char* ws = (char*)d_ws;
  float* P  = (float*)ws;                                   // 8*HN floats = 256 KB
  float* WT = (float*)(ws + 8 * HN * sizeof(float));        // 512 KB
  size_t OFF_U  = (size_t)1 << 20;
  size_t OFF_SF = OFF_U + (size_t)BH * LL * sizeof(float);  // 1MB + 128MB
  size_t OFF_SB = OFF_SF + (size_t)BH * NG * 64 * sizeof(float); // +16MB
  float* U  = (float*)(ws + OFF_U);
  float* SF = (float*)(ws + OFF_SF);
  float* SB = (float*)(ws + OFF_SB);

  precomp_kernel<<<HN / 256, 256, 0, stream>>>(log_dt, A_real, A_imag, C_real, C_imag, P);
  wt_kernel<<<512, 256, 0, stream>>>(W, WT);
  transpose_kernel<<<dim3(BH / 32, LL / 32), dim3(32, 8), 0, stream>>>(x, U);
  scanA<<<(BH * NG) / 64, 256, 0, stream>>>(U, P, SF, SB);
  scanB<<<(BH * NHD) / 256, 256, 0, stream>>>(P, SF, SB);
  scanC_bwd<<<(BH * NG) / 64, 256, 0, stream>>>(U, P, SB, (float*)d_out);
  scanC_fwd<<<(BH * NG) / 64, 256, 0, stream>>>(U, P, SF, (const float*)d_out, Dv);
  gemm_kernel<<<BB * (LL / 32), 256, 0, stream>>>(U, WT, bvec, out);
}

// Round 3
// 914.493 us; speedup vs baseline: 1.5260x; 1.1765x over previous
//
#include <hip/hip_runtime.h>
#include <hip/hip_bf16.h>
#include <math.h>

#define HH  256      // d_model
#define NHD 32       // state halves
#define LL  8192     // sequence length
#define BB  16       // batch
#define HN  (HH*NHD) // 8192
#define BH  (BB*HH)  // 4096
#define LC  512      // chunk length
#define NG  (LL/LC)  // 16 chunks per row
#define NIT (LC/16)  // 32 sub-iters per chunk

typedef __attribute__((ext_vector_type(8))) short short8;
typedef __attribute__((ext_vector_type(4))) float floatx4;

// bf16 round-to-nearest-even helpers
__device__ __forceinline__ unsigned short f2bf(float f) {
  unsigned u = __float_as_uint(f);
  unsigned r = (u + 0x7FFF + ((u >> 16) & 1)) >> 16;
  return (unsigned short)r;
}
__device__ __forceinline__ float bf2f(unsigned short s) {
  return __uint_as_float((unsigned)s << 16);
}

// ---------------------------------------------------------------------------
// Param precompute (double precision, tiny): w = exp(dtA), c = 2*C*expm1(dtA)/A
// Layout P[k*HN + h*NHD + n], k: 0=wr 1=wi 2=c0r 3=c0i 4=c1r 5=c1i 6=wLr 7=wLi
// ---------------------------------------------------------------------------
__global__ void precomp_kernel(const float* __restrict__ log_dt,
                               const float* __restrict__ A_real,
                               const float* __restrict__ A_imag,
                               const float* __restrict__ C_real,
                               const float* __restrict__ C_imag,
                               float* __restrict__ P) {
  int i = blockIdx.x * blockDim.x + threadIdx.x;
  if (i >= HN) return;
  int h = i >> 5;
  double dt  = exp((double)log_dt[h]);
  double Are = -exp((double)A_real[i]);
  double Aim = (double)A_imag[i];
  double ar = Are * dt, ai = Aim * dt;
  double ea = exp(ar);
  double wr = ea * cos(ai), wi = ea * sin(ai);
  double em_r = wr - 1.0, em_i = wi;                 // expm1(dtA)
  double den = Are * Are + Aim * Aim;
  double rr = (em_r * Are + em_i * Aim) / den;       // expm1(dtA)/A
  double ri = (em_i * Are - em_r * Aim) / den;
  P[0*HN + i] = (float)wr;
  P[1*HN + i] = (float)wi;
  {
    double cr = (double)C_real[i], ci = (double)C_imag[i];
    P[2*HN + i] = (float)(2.0 * (cr * rr - ci * ri));
    P[3*HN + i] = (float)(2.0 * (cr * ri + ci * rr));
  }
  {
    double cr = (double)C_real[HN + i], ci = (double)C_imag[HN + i];
    P[4*HN + i] = (float)(2.0 * (cr * rr - ci * ri));
    P[5*HN + i] = (float)(2.0 * (cr * ri + ci * rr));
  }
  {
    double arL = ar * (double)LC, aiL = ai * (double)LC;
    double eaL = exp(arL);
    P[6*HN + i] = (float)(eaL * cos(aiL));
    P[7*HN + i] = (float)(eaL * sin(aiL));
  }
}

// ---------------------------------------------------------------------------
// W_out (512,256) -> WT (256,512)  [fallback path]
// ---------------------------------------------------------------------------
__global__ void wt_kernel(const float* __restrict__ W, float* __restrict__ WT) {
  int idx = blockIdx.x * blockDim.x + threadIdx.x;
  if (idx >= 512 * HH) return;
  int o = idx & 511, h = idx >> 9;
  WT[idx] = W[o * HH + h];
}

// W (512,256) row-major -> bf16 hi/lo planes, same layout (MFMA path)
__global__ void wt_split_kernel(const float* __restrict__ W,
                                unsigned short* __restrict__ Whi,
                                unsigned short* __restrict__ Wlo) {
  int idx = blockIdx.x * 256 + threadIdx.x;   // 512*256 = 131072
  float v = W[idx];
  unsigned short hi = f2bf(v);
  Whi[idx] = hi;
  Wlo[idx] = f2bf(v - bf2f(hi));
}

// ---------------------------------------------------------------------------
// x (L, B*H) -> U (B*H, L)  tiled transpose
// ---------------------------------------------------------------------------
__global__ void transpose_kernel(const float* __restrict__ x, float* __restrict__ U) {
  __shared__ float tile[32][33];
  int gx = blockIdx.x * 32;   // p = b*H + h
  int gy = blockIdx.y * 32;   // t
  int tx = threadIdx.x, ty = threadIdx.y;
  #pragma unroll
  for (int k2 = 0; k2 < 4; ++k2)
    tile[ty + 8*k2][tx] = x[(size_t)(gy + ty + 8*k2) * BH + gx + tx];
  __syncthreads();
  #pragma unroll
  for (int k2 = 0; k2 < 4; ++k2)
    U[(size_t)(gx + ty + 8*k2) * LL + gy + tx] = tile[tx][ty + 8*k2];
}

// ---------------------------------------------------------------------------
// U (B*H, L) f32 -> Yhi/Ylo (B*L, H) bf16 planes (k-contiguous for MFMA B-frags)
// ---------------------------------------------------------------------------
__global__ void convT_kernel(const float* __restrict__ U,
                             unsigned short* __restrict__ Yhi,
                             unsigned short* __restrict__ Ylo) {
  __shared__ float tile[32][33];
  int pb = blockIdx.x * 32;   // p tile
  int lb = blockIdx.y * 32;   // l tile
  int tx = threadIdx.x, ty = threadIdx.y;
  #pragma unroll
  for (int k2 = 0; k2 < 4; ++k2)
    tile[ty + 8*k2][tx] = U[(size_t)(pb + ty + 8*k2) * LL + lb + tx];
  __syncthreads();
  int b = pb >> 8, h0 = pb & 255;
  #pragma unroll
  for (int k2 = 0; k2 < 4; ++k2) {
    int r = ty + 8*k2;
    float v = tile[tx][r];
    size_t o = (size_t)(b * LL + lb + r) * HH + h0 + tx;
    unsigned short hi = f2bf(v);
    Yhi[o] = hi;
    Ylo[o] = f2bf(v - bf2f(hi));
  }
}

// ---------------------------------------------------------------------------
// quad (4-lane) DPP helpers
// ---------------------------------------------------------------------------
template<int CTRL>
__device__ __forceinline__ float qbcast(float v) {
  int t = __builtin_amdgcn_update_dpp(0, __float_as_int(v), CTRL, 0xF, 0xF, true);
  return __int_as_float(t);
}
template<int CTRL>
__device__ __forceinline__ float qadd(float v) {
  int t = __builtin_amdgcn_update_dpp(0, __float_as_int(v), CTRL, 0xF, 0xF, true);
  return v + __int_as_float(t);
}

// ---------------------------------------------------------------------------
// step primitives: 8 complex states per lane
// ---------------------------------------------------------------------------
__device__ __forceinline__ void upd8(float ub, float (&sr)[8], float (&si)[8],
                                     const float (&wr)[8], const float (&wi)[8]) {
  #pragma unroll
  for (int q = 0; q < 8; ++q) {
    float t  = fmaf(wr[q], sr[q], ub);
    float ni = fmaf(wi[q], sr[q], wr[q] * si[q]);
    sr[q] = fmaf(-wi[q], si[q], t);
    si[q] = ni;
  }
}
__device__ __forceinline__ float fwd_step(float ub, float (&sr)[8], float (&si)[8],
    const float (&wr)[8], const float (&wi)[8],
    const float (&cr)[8], const float (&ci)[8]) {
  float c = 0.f;
  #pragma unroll
  for (int q = 0; q < 8; ++q) {
    float t  = fmaf(wr[q], sr[q], ub);
    float ni = fmaf(wi[q], sr[q], wr[q] * si[q]);
    sr[q] = fmaf(-wi[q], si[q], t);
    si[q] = ni;
    c = fmaf(cr[q], sr[q], c);
    c = fmaf(-ci[q], si[q], c);
  }
  return c;
}
__device__ __forceinline__ float bwd_step(float ub, float (&sr)[8], float (&si)[8],
    const float (&wr)[8], const float (&wi)[8],
    const float (&cr)[8], const float (&ci)[8]) {
  float c = 0.f;
  #pragma unroll
  for (int q = 0; q < 8; ++q) {
    c = fmaf(cr[q], sr[q], c);
    c = fmaf(-ci[q], si[q], c);
    float t  = fmaf(wr[q], sr[q], ub);
    float ni = fmaf(wi[q], sr[q], wr[q] * si[q]);
    sr[q] = fmaf(-wi[q], si[q], t);
    si[q] = ni;
  }
  return c;
}

// ---------------------------------------------------------------------------
// Pass A: per-(row,chunk) local final states, both directions, zero init.
// ---------------------------------------------------------------------------
__global__ __launch_bounds__(256) void scanA(const float* __restrict__ U,
                                             const float* __restrict__ P,
                                             float* __restrict__ SF,
                                             float* __restrict__ SB) {
  int tid = threadIdx.x;
  int gl  = tid & 3;
  int grp = (blockIdx.x << 6) | (tid >> 2);
  int p = grp >> 4, g = grp & (NG - 1), h = p & (HH - 1);
  const float* Pb = P + h * NHD + gl * 8;
  float wr[8], wi[8];
  #pragma unroll
  for (int q = 0; q < 8; ++q) { wr[q] = Pb[q]; wi[q] = Pb[HN + q]; }
  float fr[8], fi[8], br[8], bi[8];
  #pragma unroll
  for (int q = 0; q < 8; ++q) { fr[q] = 0.f; fi[q] = 0.f; br[q] = 0.f; bi[q] = 0.f; }
  size_t base = (size_t)p * LL + (size_t)g * LC;
  const float* up = U + base;

#define AF(J2, CMP) { float ubv = qbcast<(J2)*0x55>(uf.CMP); upd8(ubv, fr, fi, wr, wi); }
#define AB(J2, CMP) { float ubv = qbcast<(J2)*0x55>(ub4.CMP); upd8(ubv, br, bi, wr, wi); }
  for (int ii = 0; ii < NIT; ++ii) {
    float4 uf  = ((const float4*)(up + 16 * ii))[gl];
    float4 ub4 = ((const float4*)(up + (LC - 16) - 16 * ii))[gl];
    AF(0,x) AF(0,y) AF(0,z) AF(0,w)
    AF(1,x) AF(1,y) AF(1,z) AF(1,w)
    AF(2,x) AF(2,y) AF(2,z) AF(2,w)
    AF(3,x) AF(3,y) AF(3,z) AF(3,w)
    AB(3,w) AB(3,z) AB(3,y) AB(3,x)
    AB(2,w) AB(2,z) AB(2,y) AB(2,x)
    AB(1,w) AB(1,z) AB(1,y) AB(1,x)
    AB(0,w) AB(0,z) AB(0,y) AB(0,x)
  }
#undef AF
#undef AB
  float* of = SF + (size_t)grp * 64 + gl * 16;
  float* ob = SB + (size_t)grp * 64 + gl * 16;
  #pragma unroll
  for (int q = 0; q < 8; ++q) {
    of[2*q] = fr[q]; of[2*q+1] = fi[q];
    ob[2*q] = br[q]; ob[2*q+1] = bi[q];
  }
}

// ---------------------------------------------------------------------------
// Pass B: cross-chunk state scan, in place.
// ---------------------------------------------------------------------------
__global__ __launch_bounds__(256) void scanB(const float* __restrict__ P,
                                             float* __restrict__ SF,
                                             float* __restrict__ SB) {
  int t = blockIdx.x * 256 + threadIdx.x;
  if (t >= BH * NHD) return;
  int p = t >> 5, n = t & 31, h = p & (HH - 1);
  float wlr = P[6*HN + h*NHD + n], wli = P[7*HN + h*NHD + n];
  {
    float* f = SF + (size_t)p * NG * 64 + 2 * n;
    float ar = 0.f, ai = 0.f;
    for (int g = 0; g < NG; ++g) {
      float lr = f[g*64], li = f[g*64+1];
      f[g*64] = ar; f[g*64+1] = ai;
      float nr = lr + wlr * ar - wli * ai;
      float ni = li + wlr * ai + wli * ar;
      ar = nr; ai = ni;
    }
  }
  {
    float* b = SB + (size_t)p * NG * 64 + 2 * n;
    float ar = 0.f, ai = 0.f;
    for (int g = NG - 1; g >= 0; --g) {
      float lr = b[g*64], li = b[g*64+1];
      b[g*64] = ar; b[g*64+1] = ai;
      float nr = lr + wlr * ar - wli * ai;
      float ni = li + wlr * ai + wli * ar;
      ar = nr; ai = ni;
    }
  }
}

// ---------------------------------------------------------------------------
// Pass C backward: y_b partials -> YB (d_out).
// ---------------------------------------------------------------------------
__global__ __launch_bounds__(256) void scanC_bwd(const float* __restrict__ U,
                                                 const float* __restrict__ P,
                                                 const float* __restrict__ Sin,
                                                 float* __restrict__ YB) {
  int tid = threadIdx.x;
  int gl  = tid & 3;
  int grp = (blockIdx.x << 6) | (tid >> 2);
  int p = grp >> 4, g = grp & (NG - 1), h = p & (HH - 1);
  const float* Pb = P + h * NHD + gl * 8;
  float wr[8], wi[8], cr[8], ci[8];
  #pragma unroll
  for (int q = 0; q < 8; ++q) {
    wr[q] = Pb[q];        wi[q] = Pb[HN + q];
    cr[q] = Pb[4*HN + q]; ci[q] = Pb[5*HN + q];
  }
  float sr[8], si[8];
  const float* sp = Sin + (size_t)grp * 64 + gl * 16;
  #pragma unroll
  for (int q = 0; q < 8; ++q) { sr[q] = sp[2*q]; si[q] = sp[2*q+1]; }
  size_t base = (size_t)p * LL + (size_t)g * LC;
  const float* up = U + base;
  float* yp = YB + base;

#define QB(J2, CMP, ACC) { \
    float ubv = qbcast<(J2)*0x55>(u4.CMP); \
    float c = bwd_step(ubv, sr, si, wr, wi, cr, ci); \
    c = qadd<0xB1>(c); c = qadd<0x4E>(c); \
    ACC = (gl == (J2)) ? c : ACC; }
  for (int ii = NIT - 1; ii >= 0; --ii) {
    float4 u4 = ((const float4*)(up + 16 * ii))[gl];
    float a0 = 0.f, a1 = 0.f, a2 = 0.f, a3 = 0.f;
    QB(3,w,a3) QB(3,z,a2) QB(3,y,a1) QB(3,x,a0)
    QB(2,w,a3) QB(2,z,a2) QB(2,y,a1) QB(2,x,a0)
    QB(1,w,a3) QB(1,z,a2) QB(1,y,a1) QB(1,x,a0)
    QB(0,w,a3) QB(0,z,a2) QB(0,y,a1) QB(0,x,a0)
    float4 o4; o4.x = a0; o4.y = a1; o4.z = a2; o4.w = a3;
    ((float4*)(yp + 16 * ii))[gl] = o4;
  }
#undef QB
}

// ---------------------------------------------------------------------------
// Pass C forward: combine y_f + y_b + D*u, gelu, write over U in place.
// ---------------------------------------------------------------------------
__device__ __forceinline__ float gelu_t(float y) {
  float y2 = y * y;
  float arg = 1.5957691216f * fmaf(0.044715f * y2, y, y);
  return y / (1.f + __expf(-arg));
}
__global__ __launch_bounds__(256) void scanC_fwd(float* __restrict__ U,
                                                 const float* __restrict__ P,
                                                 const float* __restrict__ Sin,
                                                 const float* __restrict__ YB,
                                                 const float* __restrict__ Dv) {
  int tid = threadIdx.x;
  int gl  = tid & 3;
  int grp = (blockIdx.x << 6) | (tid >> 2);
  int p = grp >> 4, g = grp & (NG - 1), h = p & (HH - 1);
  const float* Pb = P + h * NHD + gl * 8;
  float wr[8], wi[8], cr[8], ci[8];
  #pragma unroll
  for (int q = 0; q < 8; ++q) {
    wr[q] = Pb[q];        wi[q] = Pb[HN + q];
    cr[q] = Pb[2*HN + q]; ci[q] = Pb[3*HN + q];
  }
  float dh = Dv[h];
  float sr[8], si[8];
  const float* sp = Sin + (size_t)grp * 64 + gl * 16;
  #pragma unroll
  for (int q = 0; q < 8; ++q) { sr[q] = sp[2*q]; si[q] = sp[2*q+1]; }
  size_t base = (size_t)p * LL + (size_t)g * LC;
  float* up = U + base;
  const float* ybp = YB + base;

#define QF(J2, CMP, ACC) { \
    float ubv = qbcast<(J2)*0x55>(u4.CMP); \
    float c = fwd_step(ubv, sr, si, wr, wi, cr, ci); \
    c = qadd<0xB1>(c); c = qadd<0x4E>(c); \
    ACC = (gl == (J2)) ? c : ACC; }
  for (int ii = 0; ii < NIT; ++ii) {
    float4 u4  = ((const float4*)(up + 16 * ii))[gl];
    float4 yb4 = ((const float4*)(ybp + 16 * ii))[gl];
    float a0 = 0.f, a1 = 0.f, a2 = 0.f, a3 = 0.f;
    QF(0,x,a0) QF(0,y,a1) QF(0,z,a2) QF(0,w,a3)
    QF(1,x,a0) QF(1,y,a1) QF(1,z,a2) QF(1,w,a3)
    QF(2,x,a0) QF(2,y,a1) QF(2,z,a2) QF(2,w,a3)
    QF(3,x,a0) QF(3,y,a1) QF(3,z,a2) QF(3,w,a3)
    float4 o4;
    o4.x = gelu_t(a0 + yb4.x + dh * u4.x);
    o4.y = gelu_t(a1 + yb4.y + dh * u4.y);
    o4.z = gelu_t(a2 + yb4.z + dh * u4.z);
    o4.w = gelu_t(a3 + yb4.w + dh * u4.w);
    ((float4*)(up + 16 * ii))[gl] = o4;
  }
#undef QF
}

// ---------------------------------------------------------------------------
// MFMA GEMM + GLU. Split-bf16: z = Whi*yhi + Whi*ylo + Wlo*yhi.
// Block: 8 waves, full M=512, BN=128 cols. Wave w owns o-rows
// [w*32,w*32+32) u [256+w*32, 256+w*32+32) so GLU pairs are lane-local.
// All fragments load straight from global (k-contiguous 16B per lane).
// ---------------------------------------------------------------------------
__global__ __launch_bounds__(512, 2) void gemm_mfma(
    const unsigned short* __restrict__ Whi, const unsigned short* __restrict__ Wlo,
    const unsigned short* __restrict__ Yhi, const unsigned short* __restrict__ Ylo,
    const float* __restrict__ bvec, float* __restrict__ out) {
  int tid  = threadIdx.x;
  int w    = tid >> 6;
  int lane = tid & 63;
  int ln = lane & 15, lg = lane >> 4;
  int b  = blockIdx.x >> 6;
  int l0 = (blockIdx.x & 63) << 7;

  const short8* Wh8 = (const short8*)Whi;
  const short8* Wl8 = (const short8*)Wlo;
  const short8* Yh8 = (const short8*)Yhi;
  const short8* Yl8 = (const short8*)Ylo;

  floatx4 acc[4][8];
  #pragma unroll
  for (int m = 0; m < 4; ++m)
    #pragma unroll
    for (int n = 0; n < 8; ++n) acc[m][n] = (floatx4){0.f, 0.f, 0.f, 0.f};

  size_t ybase = ((size_t)(b * LL + l0) + ln) * 32 + lg;  // short8 units: row*32
  int ob0 = w * 32 + ln;

  #pragma unroll
  for (int ks = 0; ks < 8; ++ks) {
    short8 Bh[8], Bl[8];
    size_t yb = ybase + ks * 4;
    #pragma unroll
    for (int nf = 0; nf < 8; ++nf) {
      Bh[nf] = Yh8[yb + (size_t)nf * 16 * 32];
      Bl[nf] = Yl8[yb + (size_t)nf * 16 * 32];
    }
    #pragma unroll
    for (int mm = 0; mm < 4; ++mm) {
      int orow = ob0 + ((mm & 1) << 4) + ((mm >> 1) << 8);
      size_t ai = (size_t)orow * 32 + ks * 4 + lg;
      short8 Ah = Wh8[ai];
      short8 Al = Wl8[ai];
      #pragma unroll
      for (int nf = 0; nf < 8; ++nf)
        acc[mm][nf] = __builtin_amdgcn_mfma_f32_16x16x32_bf16(Ah, Bh[nf], acc[mm][nf], 0, 0, 0);
      #pragma unroll
      for (int nf = 0; nf < 8; ++nf)
        acc[mm][nf] = __builtin_amdgcn_mfma_f32_16x16x32_bf16(Ah, Bl[nf], acc[mm][nf], 0, 0, 0);
      #pragma unroll
      for (int nf = 0; nf < 8; ++nf)
        acc[mm][nf] = __builtin_amdgcn_mfma_f32_16x16x32_bf16(Al, Bh[nf], acc[mm][nf], 0, 0, 0);
    }
  }

  // epilogue: bias + GLU, D layout col=lane&15, row=(lane>>4)*4+reg
  #pragma unroll
  for (int mm = 0; mm < 2; ++mm) {
    int obase = w * 32 + (mm << 4) + lg * 4;
    #pragma unroll
    for (int r = 0; r < 4; ++r) {
      float b0 = bvec[obase + r];
      float b1 = bvec[HH + obase + r];
      float* op = out + ((size_t)(b * HH + obase + r)) * LL + l0 + ln;
      #pragma unroll
      for (int nf = 0; nf < 8; ++nf) {
        float z1 = acc[mm][nf][r] + b0;
        float z2 = acc[mm + 2][nf][r] + b1;
        op[nf * 16] = z1 / (1.f + __expf(-z2));
      }
    }
  }
}

// ---------------------------------------------------------------------------
// Fallback f32 GEMM (used only if ws too small for the MFMA path)
// ---------------------------------------------------------------------------
__global__ __launch_bounds__(256, 4) void gemm_kernel(const float* __restrict__ Y,
                                                      const float* __restrict__ WT,
                                                      const float* __restrict__ bvec,
                                                      float* __restrict__ out) {
  __shared__ float ytile[HH][36];
  int tid = threadIdx.x;
  int b   = blockIdx.x >> 8;
  int l0  = (blockIdx.x & 255) << 5;
  const float* yrow = Y + ((size_t)b * HH + tid) * LL + l0;
  float4* drow = (float4*)&ytile[tid][0];
  #pragma unroll
  for (int jj = 0; jj < 8; ++jj)
    drow[jj] = ((const float4*)yrow)[jj];
  __syncthreads();
  float acc0[32], acc1[32];
  #pragma unroll
  for (int j = 0; j < 32; ++j) { acc0[j] = 0.f; acc1[j] = 0.f; }
  #pragma unroll 2
  for (int h = 0; h < HH; ++h) {
    float w0 = WT[h * 512 + tid];
    float w1 = WT[h * 512 + 256 + tid];
    const float4* r = (const float4*)&ytile[h][0];
    #pragma unroll
    for (int jj = 0; jj < 8; ++jj) {
      float4 y4 = r[jj];
      acc0[4*jj+0] = fmaf(w0, y4.x, acc0[4*jj+0]);
      acc0[4*jj+1] = fmaf(w0, y4.y, acc0[4*jj+1]);
      acc0[4*jj+2] = fmaf(w0, y4.z, acc0[4*jj+2]);
      acc0[4*jj+3] = fmaf(w0, y4.w, acc0[4*jj+3]);
      acc1[4*jj+0] = fmaf(w1, y4.x, acc1[4*jj+0]);
      acc1[4*jj+1] = fmaf(w1, y4.y, acc1[4*jj+1]);
      acc1[4*jj+2] = fmaf(w1, y4.z, acc1[4*jj+2]);
      acc1[4*jj+3] = fmaf(w1, y4.w, acc1[4*jj+3]);
    }
  }
  float b0 = bvec[tid], b1 = bvec[HH + tid];
  float* orow = out + ((size_t)b * HH + tid) * LL + l0;
  #pragma unroll
  for (int j = 0; j < 32; ++j) {
    float z1 = acc0[j] + b0;
    float z2 = acc1[j] + b1;
    orow[j] = z1 * (1.0f / (1.0f + __expf(-z2)));
  }
}

// ---------------------------------------------------------------------------
extern "C" void kernel_launch(void* const* d_in, const int* in_sizes, int n_in,
                              void* d_out, int out_size, void* d_ws, size_t ws_size,
                              hipStream_t stream) {
  const float* x      = (const float*)d_in[0];
  const float* log_dt = (const float*)d_in[1];
  const float* A_real = (const float*)d_in[2];
  const float* A_imag = (const float*)d_in[3];
  const float* C_real = (const float*)d_in[4];
  const float* C_imag = (const float*)d_in[5];
  const float* Dv     = (const float*)d_in[6];
  const float* W      = (const float*)d_in[7];
  const float* bvec   = (const float*)d_in[8];
  float* out = (float*)d_out;

  char* ws = (char*)d_ws;
  float*          P   = (float*)ws;                       // 256 KB
  float*          WT  = (float*)(ws + 262144);            // 512 KB (fallback)
  unsigned short* Whi = (unsigned short*)(ws + 786432);   // 256 KB
  unsigned short* Wlo = (unsigned short*)(ws + 1048576);  // 256 KB
  size_t OFF_U   = (size_t)2 << 20;
  size_t U_BYTES = (size_t)BH * LL * 4;                   // 128 MB
  size_t S_BYTES = (size_t)BH * NG * 64 * 4;              // 16 MB each
  size_t OFF_SF  = OFF_U + U_BYTES;
  size_t OFF_SB  = OFF_SF + S_BYTES;
  size_t OFF_YH  = OFF_SB + S_BYTES;
  size_t Y_BYTES = (size_t)BB * LL * HH * 2;              // 64 MB each
  size_t OFF_YL  = OFF_YH + Y_BYTES;
  size_t NEED    = OFF_YL + Y_BYTES;                      // ~290 MB
  float* U  = (float*)(ws + OFF_U);
  float* SF = (float*)(ws + OFF_SF);
  float* SB = (float*)(ws + OFF_SB);
  unsigned short* Yhi = (unsigned short*)(ws + OFF_YH);
  unsigned short* Ylo = (unsigned short*)(ws + OFF_YL);

  bool mfma_path = (ws_size >= NEED);

  precomp_kernel<<<HN / 256, 256, 0, stream>>>(log_dt, A_real, A_imag, C_real, C_imag, P);
  if (mfma_path)
    wt_split_kernel<<<512, 256, 0, stream>>>(W, Whi, Wlo);
  else
    wt_kernel<<<512, 256, 0, stream>>>(W, WT);
  transpose_kernel<<<dim3(BH / 32, LL / 32), dim3(32, 8), 0, stream>>>(x, U);
  scanA<<<(BH * NG) / 64, 256, 0, stream>>>(U, P, SF, SB);
  scanB<<<(BH * NHD) / 256, 256, 0, stream>>>(P, SF, SB);
  scanC_bwd<<<(BH * NG) / 64, 256, 0, stream>>>(U, P, SB, (float*)d_out);
  scanC_fwd<<<(BH * NG) / 64, 256, 0, stream>>>(U, P, SF, (const float*)d_out, Dv);
  if (mfma_path) {
    convT_kernel<<<dim3(BH / 32, LL / 32), dim3(32, 8), 0, stream>>>(U, Yhi, Ylo);
    gemm_mfma<<<BB * (LL / 128), 512, 0, stream>>>(Whi, Wlo, Yhi, Ylo, bvec, out);
  } else {
    gemm_kernel<<<BB * (LL / 32), 256, 0, stream>>>(U, WT, bvec, out);
  }
}

// Round 4
// 910.801 us; speedup vs baseline: 1.5322x; 1.0041x over previous
//
#include <hip/hip_runtime.h>
#include <hip/hip_bf16.h>
#include <math.h>

#define HH  256      // d_model
#define NHD 32       // state halves
#define LL  8192     // sequence length
#define BB  16       // batch
#define HN  (HH*NHD) // 8192
#define BH  (BB*HH)  // 4096
#define LC  512      // chunk length
#define NG  (LL/LC)  // 16 chunks per row
#define NIT (LC/16)  // 32 sub-iters per chunk

typedef __attribute__((ext_vector_type(8))) short short8;
typedef __attribute__((ext_vector_type(4))) float floatx4;
typedef __attribute__((ext_vector_type(2))) float f32x2;

// ---------------------------------------------------------------------------
// packed f32 math (v_pk_fma_f32: 2 FMAs / instruction / lane)
// ---------------------------------------------------------------------------
__device__ __forceinline__ f32x2 pk_fma(f32x2 a, f32x2 b, f32x2 c) {
  f32x2 d;
  asm("v_pk_fma_f32 %0, %1, %2, %3" : "=v"(d) : "v"(a), "v"(b), "v"(c));
  return d;
}
__device__ __forceinline__ f32x2 pk_mul(f32x2 a, f32x2 b) {
  f32x2 d;
  asm("v_pk_mul_f32 %0, %1, %2" : "=v"(d) : "v"(a), "v"(b));
  return d;
}
__device__ __forceinline__ void pk_fma_acc(f32x2& c, f32x2 a, f32x2 b) {
  asm("v_pk_fma_f32 %0, %1, %2, %0" : "+v"(c) : "v"(a), "v"(b));
}

// bf16 round-to-nearest-even helpers
__device__ __forceinline__ unsigned short f2bf(float f) {
  unsigned u = __float_as_uint(f);
  unsigned r = (u + 0x7FFF + ((u >> 16) & 1)) >> 16;
  return (unsigned short)r;
}
__device__ __forceinline__ float bf2f(unsigned short s) {
  return __uint_as_float((unsigned)s << 16);
}

// ---------------------------------------------------------------------------
// Param precompute (double precision, tiny): w = exp(dtA), c = 2*C*expm1(dtA)/A
// Layout P[k*HN + h*NHD + n], k: 0=wr 1=wi 2=c0r 3=c0i 4=c1r 5=c1i 6=wLr 7=wLi
// ---------------------------------------------------------------------------
__global__ void precomp_kernel(const float* __restrict__ log_dt,
                               const float* __restrict__ A_real,
                               const float* __restrict__ A_imag,
                               const float* __restrict__ C_real,
                               const float* __restrict__ C_imag,
                               float* __restrict__ P) {
  int i = blockIdx.x * blockDim.x + threadIdx.x;
  if (i >= HN) return;
  int h = i >> 5;
  double dt  = exp((double)log_dt[h]);
  double Are = -exp((double)A_real[i]);
  double Aim = (double)A_imag[i];
  double ar = Are * dt, ai = Aim * dt;
  double ea = exp(ar);
  double wr = ea * cos(ai), wi = ea * sin(ai);
  double em_r = wr - 1.0, em_i = wi;                 // expm1(dtA)
  double den = Are * Are + Aim * Aim;
  double rr = (em_r * Are + em_i * Aim) / den;       // expm1(dtA)/A
  double ri = (em_i * Are - em_r * Aim) / den;
  P[0*HN + i] = (float)wr;
  P[1*HN + i] = (float)wi;
  {
    double cr = (double)C_real[i], ci = (double)C_imag[i];
    P[2*HN + i] = (float)(2.0 * (cr * rr - ci * ri));
    P[3*HN + i] = (float)(2.0 * (cr * ri + ci * rr));
  }
  {
    double cr = (double)C_real[HN + i], ci = (double)C_imag[HN + i];
    P[4*HN + i] = (float)(2.0 * (cr * rr - ci * ri));
    P[5*HN + i] = (float)(2.0 * (cr * ri + ci * rr));
  }
  {
    double arL = ar * (double)LC, aiL = ai * (double)LC;
    double eaL = exp(arL);
    P[6*HN + i] = (float)(eaL * cos(aiL));
    P[7*HN + i] = (float)(eaL * sin(aiL));
  }
}

// ---------------------------------------------------------------------------
// W_out (512,256) -> WT (256,512)  [fallback path]
// ---------------------------------------------------------------------------
__global__ void wt_kernel(const float* __restrict__ W, float* __restrict__ WT) {
  int idx = blockIdx.x * blockDim.x + threadIdx.x;
  if (idx >= 512 * HH) return;
  int o = idx & 511, h = idx >> 9;
  WT[idx] = W[o * HH + h];
}

// W (512,256) row-major -> bf16 hi/lo planes, same layout (MFMA path)
__global__ void wt_split_kernel(const float* __restrict__ W,
                                unsigned short* __restrict__ Whi,
                                unsigned short* __restrict__ Wlo) {
  int idx = blockIdx.x * 256 + threadIdx.x;
  float v = W[idx];
  unsigned short hi = f2bf(v);
  Whi[idx] = hi;
  Wlo[idx] = f2bf(v - bf2f(hi));
}

// ---------------------------------------------------------------------------
// x (L, B*H) -> U (B*H, L)  tiled transpose
// ---------------------------------------------------------------------------
__global__ void transpose_kernel(const float* __restrict__ x, float* __restrict__ U) {
  __shared__ float tile[32][33];
  int gx = blockIdx.x * 32;   // p = b*H + h
  int gy = blockIdx.y * 32;   // t
  int tx = threadIdx.x, ty = threadIdx.y;
  #pragma unroll
  for (int k2 = 0; k2 < 4; ++k2)
    tile[ty + 8*k2][tx] = x[(size_t)(gy + ty + 8*k2) * BH + gx + tx];
  __syncthreads();
  #pragma unroll
  for (int k2 = 0; k2 < 4; ++k2)
    U[(size_t)(gx + ty + 8*k2) * LL + gy + tx] = tile[tx][ty + 8*k2];
}

// ---------------------------------------------------------------------------
// U (B*H, L) f32 -> Yhi/Ylo (B*L, H) bf16 planes (k-contiguous for MFMA B-frags)
// ---------------------------------------------------------------------------
__global__ void convT_kernel(const float* __restrict__ U,
                             unsigned short* __restrict__ Yhi,
                             unsigned short* __restrict__ Ylo) {
  __shared__ float tile[32][33];
  int pb = blockIdx.x * 32;   // p tile
  int lb = blockIdx.y * 32;   // l tile
  int tx = threadIdx.x, ty = threadIdx.y;
  #pragma unroll
  for (int k2 = 0; k2 < 4; ++k2)
    tile[ty + 8*k2][tx] = U[(size_t)(pb + ty + 8*k2) * LL + lb + tx];
  __syncthreads();
  int b = pb >> 8, h0 = pb & 255;
  #pragma unroll
  for (int k2 = 0; k2 < 4; ++k2) {
    int r = ty + 8*k2;
    float v = tile[tx][r];
    size_t o = (size_t)(b * LL + lb + r) * HH + h0 + tx;
    unsigned short hi = f2bf(v);
    Yhi[o] = hi;
    Ylo[o] = f2bf(v - bf2f(hi));
  }
}

// ---------------------------------------------------------------------------
// quad (4-lane) DPP helpers
// ---------------------------------------------------------------------------
template<int CTRL>
__device__ __forceinline__ float qbcast(float v) {
  int t = __builtin_amdgcn_update_dpp(0, __float_as_int(v), CTRL, 0xF, 0xF, true);
  return __int_as_float(t);
}
template<int CTRL>
__device__ __forceinline__ float qadd(float v) {
  int t = __builtin_amdgcn_update_dpp(0, __float_as_int(v), CTRL, 0xF, 0xF, true);
  return v + __int_as_float(t);
}

// ---------------------------------------------------------------------------
// packed step primitives: 8 complex states per lane as 4 pairs
// ---------------------------------------------------------------------------
__device__ __forceinline__ void upd4(f32x2 (&sr)[4], f32x2 (&si)[4],
                                     const f32x2 (&wr)[4], const f32x2 (&wi)[4],
                                     const f32x2 (&nwi)[4], float ub) {
  f32x2 u2; u2[0] = ub; u2[1] = ub;
  #pragma unroll
  for (int j = 0; j < 4; ++j) {
    f32x2 t   = pk_fma(wr[j], sr[j], u2);     // wr*sr + u
    f32x2 m   = pk_mul(wr[j], si[j]);         // wr*si
    f32x2 srn = pk_fma(nwi[j], si[j], t);     // -wi*si + (wr*sr + u)
    si[j] = pk_fma(wi[j], sr[j], m);          // wi*sr + wr*si
    sr[j] = srn;
  }
}
__device__ __forceinline__ float out4(const f32x2 (&sr)[4], const f32x2 (&si)[4],
                                      const f32x2 (&cr)[4], const f32x2 (&nci)[4]) {
  f32x2 a = pk_mul(cr[0], sr[0]);
  f32x2 b = pk_mul(nci[0], si[0]);
  pk_fma_acc(a, cr[1], sr[1]);  pk_fma_acc(b, nci[1], si[1]);
  pk_fma_acc(a, cr[2], sr[2]);  pk_fma_acc(b, nci[2], si[2]);
  pk_fma_acc(a, cr[3], sr[3]);  pk_fma_acc(b, nci[3], si[3]);
  return (a[0] + a[1]) + (b[0] + b[1]);
}

// ---------------------------------------------------------------------------
// Pass A: per-(row,chunk) local final states, both directions, zero init.
// Group = 4 lanes; lane gl owns n = gl*8 .. gl*8+7 (4 pairs). 64 groups/block.
// ---------------------------------------------------------------------------
__global__ __launch_bounds__(256) void scanA(const float* __restrict__ U,
                                             const float* __restrict__ P,
                                             float* __restrict__ SF,
                                             float* __restrict__ SB) {
  int tid = threadIdx.x;
  int gl  = tid & 3;
  int grp = (blockIdx.x << 6) | (tid >> 2);
  int p = grp >> 4, g = grp & (NG - 1), h = p & (HH - 1);
  const float* Pb = P + h * NHD + gl * 8;
  f32x2 wr2[4], wi2[4], nwi2[4];
  #pragma unroll
  for (int j = 0; j < 4; ++j) {
    wr2[j] = ((const f32x2*)Pb)[j];
    wi2[j] = ((const f32x2*)(Pb + HN))[j];
    nwi2[j] = -wi2[j];
  }
  f32x2 fr2[4], fi2[4], br2[4], bi2[4];
  #pragma unroll
  for (int j = 0; j < 4; ++j) {
    fr2[j] = (f32x2){0.f, 0.f}; fi2[j] = (f32x2){0.f, 0.f};
    br2[j] = (f32x2){0.f, 0.f}; bi2[j] = (f32x2){0.f, 0.f};
  }
  size_t base = (size_t)p * LL + (size_t)g * LC;
  const float* up = U + base;

#define AF(J2, CMP) { float ubv = qbcast<(J2)*0x55>(uf.CMP); upd4(fr2, fi2, wr2, wi2, nwi2, ubv); }
#define AB(J2, CMP) { float ubv = qbcast<(J2)*0x55>(ub4.CMP); upd4(br2, bi2, wr2, wi2, nwi2, ubv); }
  for (int ii = 0; ii < NIT; ++ii) {
    float4 uf  = ((const float4*)(up + 16 * ii))[gl];
    float4 ub4 = ((const float4*)(up + (LC - 16) - 16 * ii))[gl];
    AF(0,x) AF(0,y) AF(0,z) AF(0,w)
    AF(1,x) AF(1,y) AF(1,z) AF(1,w)
    AF(2,x) AF(2,y) AF(2,z) AF(2,w)
    AF(3,x) AF(3,y) AF(3,z) AF(3,w)
    AB(3,w) AB(3,z) AB(3,y) AB(3,x)
    AB(2,w) AB(2,z) AB(2,y) AB(2,x)
    AB(1,w) AB(1,z) AB(1,y) AB(1,x)
    AB(0,w) AB(0,z) AB(0,y) AB(0,x)
  }
#undef AF
#undef AB
  // store: state 2j at offset 4j (r,i), state 2j+1 at 4j+2 (r,i) -> same
  // interleaved (r,i)-per-state layout as before.
  float4* of = (float4*)(SF + (size_t)grp * 64 + gl * 16);
  float4* ob = (float4*)(SB + (size_t)grp * 64 + gl * 16);
  #pragma unroll
  for (int j = 0; j < 4; ++j) {
    float4 v;
    v.x = fr2[j][0]; v.y = fi2[j][0]; v.z = fr2[j][1]; v.w = fi2[j][1];
    of[j] = v;
    v.x = br2[j][0]; v.y = bi2[j][0]; v.z = br2[j][1]; v.w = bi2[j][1];
    ob[j] = v;
  }
}

// ---------------------------------------------------------------------------
// Pass B: cross-chunk state scan, in place.
// ---------------------------------------------------------------------------
__global__ __launch_bounds__(256) void scanB(const float* __restrict__ P,
                                             float* __restrict__ SF,
                                             float* __restrict__ SB) {
  int t = blockIdx.x * 256 + threadIdx.x;
  if (t >= BH * NHD) return;
  int p = t >> 5, n = t & 31, h = p & (HH - 1);
  float wlr = P[6*HN + h*NHD + n], wli = P[7*HN + h*NHD + n];
  {
    float* f = SF + (size_t)p * NG * 64 + 2 * n;
    float ar = 0.f, ai = 0.f;
    for (int g = 0; g < NG; ++g) {
      float lr = f[g*64], li = f[g*64+1];
      f[g*64] = ar; f[g*64+1] = ai;
      float nr = lr + wlr * ar - wli * ai;
      float ni = li + wlr * ai + wli * ar;
      ar = nr; ai = ni;
    }
  }
  {
    float* b = SB + (size_t)p * NG * 64 + 2 * n;
    float ar = 0.f, ai = 0.f;
    for (int g = NG - 1; g >= 0; --g) {
      float lr = b[g*64], li = b[g*64+1];
      b[g*64] = ar; b[g*64+1] = ai;
      float nr = lr + wlr * ar - wli * ai;
      float ni = li + wlr * ai + wli * ar;
      ar = nr; ai = ni;
    }
  }
}

// ---------------------------------------------------------------------------
// Pass C backward: y_b partials -> YB (d_out). Chunk right-to-left.
// Output uses state BEFORE absorbing u[t] (= sB[t+1]).
// ---------------------------------------------------------------------------
__global__ __launch_bounds__(256) void scanC_bwd(const float* __restrict__ U,
                                                 const float* __restrict__ P,
                                                 const float* __restrict__ Sin,
                                                 float* __restrict__ YB) {
  int tid = threadIdx.x;
  int gl  = tid & 3;
  int grp = (blockIdx.x << 6) | (tid >> 2);
  int p = grp >> 4, g = grp & (NG - 1), h = p & (HH - 1);
  const float* Pb = P + h * NHD + gl * 8;
  f32x2 wr2[4], wi2[4], nwi2[4], cr2[4], nci2[4];
  #pragma unroll
  for (int j = 0; j < 4; ++j) {
    wr2[j]  = ((const f32x2*)Pb)[j];
    wi2[j]  = ((const f32x2*)(Pb + HN))[j];
    nwi2[j] = -wi2[j];
    cr2[j]  = ((const f32x2*)(Pb + 4*HN))[j];
    nci2[j] = -((const f32x2*)(Pb + 5*HN))[j];
  }
  f32x2 sr2[4], si2[4];
  const float* sp = Sin + (size_t)grp * 64 + gl * 16;
  #pragma unroll
  for (int j = 0; j < 4; ++j) {
    sr2[j][0] = sp[4*j];   sr2[j][1] = sp[4*j+2];
    si2[j][0] = sp[4*j+1]; si2[j][1] = sp[4*j+3];
  }
  size_t base = (size_t)p * LL + (size_t)g * LC;
  const float* up = U + base;
  float* yp = YB + base;

#define QB(J2, CMP, ACC) { \
    float ubv = qbcast<(J2)*0x55>(u4.CMP); \
    float c = out4(sr2, si2, cr2, nci2); \
    upd4(sr2, si2, wr2, wi2, nwi2, ubv); \
    c = qadd<0xB1>(c); c = qadd<0x4E>(c); \
    ACC = (gl == (J2)) ? c : ACC; }
  for (int ii = NIT - 1; ii >= 0; --ii) {
    float4 u4 = ((const float4*)(up + 16 * ii))[gl];
    float a0 = 0.f, a1 = 0.f, a2 = 0.f, a3 = 0.f;
    QB(3,w,a3) QB(3,z,a2) QB(3,y,a1) QB(3,x,a0)
    QB(2,w,a3) QB(2,z,a2) QB(2,y,a1) QB(2,x,a0)
    QB(1,w,a3) QB(1,z,a2) QB(1,y,a1) QB(1,x,a0)
    QB(0,w,a3) QB(0,z,a2) QB(0,y,a1) QB(0,x,a0)
    float4 o4; o4.x = a0; o4.y = a1; o4.z = a2; o4.w = a3;
    ((float4*)(yp + 16 * ii))[gl] = o4;
  }
#undef QB
}

// ---------------------------------------------------------------------------
// Pass C forward: combine y_f + y_b + D*u, gelu, write over U in place.
// Output uses state AFTER absorbing u[t].
// ---------------------------------------------------------------------------
__device__ __forceinline__ float gelu_t(float y) {
  float y2 = y * y;
  float arg = 1.5957691216f * fmaf(0.044715f * y2, y, y);
  return y / (1.f + __expf(-arg));
}
__global__ __launch_bounds__(256) void scanC_fwd(float* __restrict__ U,
                                                 const float* __restrict__ P,
                                                 const float* __restrict__ Sin,
                                                 const float* __restrict__ YB,
                                                 const float* __restrict__ Dv) {
  int tid = threadIdx.x;
  int gl  = tid & 3;
  int grp = (blockIdx.x << 6) | (tid >> 2);
  int p = grp >> 4, g = grp & (NG - 1), h = p & (HH - 1);
  const float* Pb = P + h * NHD + gl * 8;
  f32x2 wr2[4], wi2[4], nwi2[4], cr2[4], nci2[4];
  #pragma unroll
  for (int j = 0; j < 4; ++j) {
    wr2[j]  = ((const f32x2*)Pb)[j];
    wi2[j]  = ((const f32x2*)(Pb + HN))[j];
    nwi2[j] = -wi2[j];
    cr2[j]  = ((const f32x2*)(Pb + 2*HN))[j];
    nci2[j] = -((const f32x2*)(Pb + 3*HN))[j];
  }
  float dh = Dv[h];
  f32x2 sr2[4], si2[4];
  const float* sp = Sin + (size_t)grp * 64 + gl * 16;
  #pragma unroll
  for (int j = 0; j < 4; ++j) {
    sr2[j][0] = sp[4*j];   sr2[j][1] = sp[4*j+2];
    si2[j][0] = sp[4*j+1]; si2[j][1] = sp[4*j+3];
  }
  size_t base = (size_t)p * LL + (size_t)g * LC;
  float* up = U + base;
  const float* ybp = YB + base;

#define QF(J2, CMP, ACC) { \
    float ubv = qbcast<(J2)*0x55>(u4.CMP); \
    upd4(sr2, si2, wr2, wi2, nwi2, ubv); \
    float c = out4(sr2, si2, cr2, nci2); \
    c = qadd<0xB1>(c); c = qadd<0x4E>(c); \
    ACC = (gl == (J2)) ? c : ACC; }
  for (int ii = 0; ii < NIT; ++ii) {
    float4 u4  = ((const float4*)(up + 16 * ii))[gl];
    float4 yb4 = ((const float4*)(ybp + 16 * ii))[gl];
    float a0 = 0.f, a1 = 0.f, a2 = 0.f, a3 = 0.f;
    QF(0,x,a0) QF(0,y,a1) QF(0,z,a2) QF(0,w,a3)
    QF(1,x,a0) QF(1,y,a1) QF(1,z,a2) QF(1,w,a3)
    QF(2,x,a0) QF(2,y,a1) QF(2,z,a2) QF(2,w,a3)
    QF(3,x,a0) QF(3,y,a1) QF(3,z,a2) QF(3,w,a3)
    float4 o4;
    o4.x = gelu_t(a0 + yb4.x + dh * u4.x);
    o4.y = gelu_t(a1 + yb4.y + dh * u4.y);
    o4.z = gelu_t(a2 + yb4.z + dh * u4.z);
    o4.w = gelu_t(a3 + yb4.w + dh * u4.w);
    ((float4*)(up + 16 * ii))[gl] = o4;
  }
#undef QF
}

// ---------------------------------------------------------------------------
// MFMA GEMM + GLU. Split-bf16: z = Whi*yhi + Whi*ylo + Wlo*yhi.
// ---------------------------------------------------------------------------
__global__ __launch_bounds__(512, 2) void gemm_mfma(
    const unsigned short* __restrict__ Whi, const unsigned short* __restrict__ Wlo,
    const unsigned short* __restrict__ Yhi, const unsigned short* __restrict__ Ylo,
    const float* __restrict__ bvec, float* __restrict__ out) {
  int tid  = threadIdx.x;
  int w    = tid >> 6;
  int lane = tid & 63;
  int ln = lane & 15, lg = lane >> 4;
  int b  = blockIdx.x >> 6;
  int l0 = (blockIdx.x & 63) << 7;

  const short8* Wh8 = (const short8*)Whi;
  const short8* Wl8 = (const short8*)Wlo;
  const short8* Yh8 = (const short8*)Yhi;
  const short8* Yl8 = (const short8*)Ylo;

  floatx4 acc[4][8];
  #pragma unroll
  for (int m = 0; m < 4; ++m)
    #pragma unroll
    for (int n = 0; n < 8; ++n) acc[m][n] = (floatx4){0.f, 0.f, 0.f, 0.f};

  size_t ybase = ((size_t)(b * LL + l0) + ln) * 32 + lg;
  int ob0 = w * 32 + ln;

  #pragma unroll
  for (int ks = 0; ks < 8; ++ks) {
    short8 Bh[8], Bl[8];
    size_t yb = ybase + ks * 4;
    #pragma unroll
    for (int nf = 0; nf < 8; ++nf) {
      Bh[nf] = Yh8[yb + (size_t)nf * 16 * 32];
      Bl[nf] = Yl8[yb + (size_t)nf * 16 * 32];
    }
    #pragma unroll
    for (int mm = 0; mm < 4; ++mm) {
      int orow = ob0 + ((mm & 1) << 4) + ((mm >> 1) << 8);
      size_t ai = (size_t)orow * 32 + ks * 4 + lg;
      short8 Ah = Wh8[ai];
      short8 Al = Wl8[ai];
      #pragma unroll
      for (int nf = 0; nf < 8; ++nf)
        acc[mm][nf] = __builtin_amdgcn_mfma_f32_16x16x32_bf16(Ah, Bh[nf], acc[mm][nf], 0, 0, 0);
      #pragma unroll
      for (int nf = 0; nf < 8; ++nf)
        acc[mm][nf] = __builtin_amdgcn_mfma_f32_16x16x32_bf16(Ah, Bl[nf], acc[mm][nf], 0, 0, 0);
      #pragma unroll
      for (int nf = 0; nf < 8; ++nf)
        acc[mm][nf] = __builtin_amdgcn_mfma_f32_16x16x32_bf16(Al, Bh[nf], acc[mm][nf], 0, 0, 0);
    }
  }

  #pragma unroll
  for (int mm = 0; mm < 2; ++mm) {
    int obase = w * 32 + (mm << 4) + lg * 4;
    #pragma unroll
    for (int r = 0; r < 4; ++r) {
      float b0 = bvec[obase + r];
      float b1 = bvec[HH + obase + r];
      float* op = out + ((size_t)(b * HH + obase + r)) * LL + l0 + ln;
      #pragma unroll
      for (int nf = 0; nf < 8; ++nf) {
        float z1 = acc[mm][nf][r] + b0;
        float z2 = acc[mm + 2][nf][r] + b1;
        op[nf * 16] = z1 / (1.f + __expf(-z2));
      }
    }
  }
}

// ---------------------------------------------------------------------------
// Fallback f32 GEMM (used only if ws too small for the MFMA path)
// ---------------------------------------------------------------------------
__global__ __launch_bounds__(256, 4) void gemm_kernel(const float* __restrict__ Y,
                                                      const float* __restrict__ WT,
                                                      const float* __restrict__ bvec,
                                                      float* __restrict__ out) {
  __shared__ float ytile[HH][36];
  int tid = threadIdx.x;
  int b   = blockIdx.x >> 8;
  int l0  = (blockIdx.x & 255) << 5;
  const float* yrow = Y + ((size_t)b * HH + tid) * LL + l0;
  float4* drow = (float4*)&ytile[tid][0];
  #pragma unroll
  for (int jj = 0; jj < 8; ++jj)
    drow[jj] = ((const float4*)yrow)[jj];
  __syncthreads();
  float acc0[32], acc1[32];
  #pragma unroll
  for (int j = 0; j < 32; ++j) { acc0[j] = 0.f; acc1[j] = 0.f; }
  #pragma unroll 2
  for (int h = 0; h < HH; ++h) {
    float w0 = WT[h * 512 + tid];
    float w1 = WT[h * 512 + 256 + tid];
    const float4* r = (const float4*)&ytile[h][0];
    #pragma unroll
    for (int jj = 0; jj < 8; ++jj) {
      float4 y4 = r[jj];
      acc0[4*jj+0] = fmaf(w0, y4.x, acc0[4*jj+0]);
      acc0[4*jj+1] = fmaf(w0, y4.y, acc0[4*jj+1]);
      acc0[4*jj+2] = fmaf(w0, y4.z, acc0[4*jj+2]);
      acc0[4*jj+3] = fmaf(w0, y4.w, acc0[4*jj+3]);
      acc1[4*jj+0] = fmaf(w1, y4.x, acc1[4*jj+0]);
      acc1[4*jj+1] = fmaf(w1, y4.y, acc1[4*jj+1]);
      acc1[4*jj+2] = fmaf(w1, y4.z, acc1[4*jj+2]);
      acc1[4*jj+3] = fmaf(w1, y4.w, acc1[4*jj+3]);
    }
  }
  float b0 = bvec[tid], b1 = bvec[HH + tid];
  float* orow = out + ((size_t)b * HH + tid) * LL + l0;
  #pragma unroll
  for (int j = 0; j < 32; ++j) {
    float z1 = acc0[j] + b0;
    float z2 = acc1[j] + b1;
    orow[j] = z1 * (1.0f / (1.0f + __expf(-z2)));
  }
}

// ---------------------------------------------------------------------------
extern "C" void kernel_launch(void* const* d_in, const int* in_sizes, int n_in,
                              void* d_out, int out_size, void* d_ws, size_t ws_size,
                              hipStream_t stream) {
  const float* x      = (const float*)d_in[0];
  const float* log_dt = (const float*)d_in[1];
  const float* A_real = (const float*)d_in[2];
  const float* A_imag = (const float*)d_in[3];
  const float* C_real = (const float*)d_in[4];
  const float* C_imag = (const float*)d_in[5];
  const float* Dv     = (const float*)d_in[6];
  const float* W      = (const float*)d_in[7];
  const float* bvec   = (const float*)d_in[8];
  float* out = (float*)d_out;

  char* ws = (char*)d_ws;
  float*          P   = (float*)ws;                       // 256 KB
  float*          WT  = (float*)(ws + 262144);            // 512 KB (fallback)
  unsigned short* Whi = (unsigned short*)(ws + 786432);   // 256 KB
  unsigned short* Wlo = (unsigned short*)(ws + 1048576);  // 256 KB
  size_t OFF_U   = (size_t)2 << 20;
  size_t U_BYTES = (size_t)BH * LL * 4;                   // 128 MB
  size_t S_BYTES = (size_t)BH * NG * 64 * 4;              // 16 MB each
  size_t OFF_SF  = OFF_U + U_BYTES;
  size_t OFF_SB  = OFF_SF + S_BYTES;
  size_t OFF_YH  = OFF_SB + S_BYTES;
  size_t Y_BYTES = (size_t)BB * LL * HH * 2;              // 64 MB each
  size_t OFF_YL  = OFF_YH + Y_BYTES;
  size_t NEED    = OFF_YL + Y_BYTES;                      // ~290 MB
  float* U  = (float*)(ws + OFF_U);
  float* SF = (float*)(ws + OFF_SF);
  float* SB = (float*)(ws + OFF_SB);
  unsigned short* Yhi = (unsigned short*)(ws + OFF_YH);
  unsigned short* Ylo = (unsigned short*)(ws + OFF_YL);

  bool mfma_path = (ws_size >= NEED);

  precomp_kernel<<<HN / 256, 256, 0, stream>>>(log_dt, A_real, A_imag, C_real, C_imag, P);
  if (mfma_path)
    wt_split_kernel<<<512, 256, 0, stream>>>(W, Whi, Wlo);
  else
    wt_kernel<<<512, 256, 0, stream>>>(W, WT);
  transpose_kernel<<<dim3(BH / 32, LL / 32), dim3(32, 8), 0, stream>>>(x, U);
  scanA<<<(BH * NG) / 64, 256, 0, stream>>>(U, P, SF, SB);
  scanB<<<(BH * NHD) / 256, 256, 0, stream>>>(P, SF, SB);
  scanC_bwd<<<(BH * NG) / 64, 256, 0, stream>>>(U, P, SB, (float*)d_out);
  scanC_fwd<<<(BH * NG) / 64, 256, 0, stream>>>(U, P, SF, (const float*)d_out, Dv);
  if (mfma_path) {
    convT_kernel<<<dim3(BH / 32, LL / 32), dim3(32, 8), 0, stream>>>(U, Yhi, Ylo);
    gemm_mfma<<<BB * (LL / 128), 512, 0, stream>>>(Whi, Wlo, Yhi, Ylo, bvec, out);
  } else {
    gemm_kernel<<<BB * (LL / 32), 256, 0, stream>>>(U, WT, bvec, out);
  }
}